// Round 8
// baseline (166.463 us; speedup 1.0000x reference)
//
#include <hip/hip_runtime.h>
#include <hip/hip_bf16.h>
#include <math.h>

#define NNODES 100000
#define FIN 500
#define KPAD 512
#define HIDDIM 64
#define NCLS 40
#define KORD 10

typedef __bf16 bf16x4 __attribute__((ext_vector_type(4)));
typedef __bf16 bf16x8 __attribute__((ext_vector_type(8)));
typedef float f32x4 __attribute__((ext_vector_type(4)));

// ---------------- polynomial coefficients + need-flags from temp ----------------
// out = sum_j C(K,j)/2^K * relu(temp[j]) * (I-A)^j (I+A)^{K-j} h = sum_m g[m] A^m h
// g[m] = sum_j s_j * T[j][m], T[j][m] = coeff of x^m in (1-x)^j (1+x)^{K-j}.
// All intermediates are integers/1024 with numerators < 2^24, exact in f32.
// flags[m] = 1 iff any g[j] != 0 for j >= m  (SpMV step m still needed).
__global__ void coeff_kernel(const float* __restrict__ temp, float* __restrict__ g,
                             int* __restrict__ flags) {
  if (threadIdx.x != 0 || blockIdx.x != 0) return;
  float C[KORD + 1][KORD + 1];
  for (int n = 0; n <= KORD; ++n)
    for (int k = 0; k <= KORD; ++k) C[n][k] = 0.f;
  for (int n = 0; n <= KORD; ++n) {
    C[n][0] = 1.f;
    for (int k = 1; k <= n; ++k) C[n][k] = C[n - 1][k - 1] + C[n - 1][k];
  }
  float s[KORD + 1];
  for (int j = 0; j <= KORD; ++j) {
    float th = temp[j] > 0.f ? temp[j] : 0.f;
    s[j] = C[KORD][j] * (1.0f / 1024.0f) * th;
  }
  for (int m = 0; m <= KORD; ++m) {
    float acc = 0.f;
    for (int j = 0; j <= KORD; ++j) {
      float T = 0.f;
      for (int a = 0; a <= m; ++a) {
        int b = m - a;
        if (a <= j && b <= KORD - j)
          T += ((a & 1) ? -1.f : 1.f) * C[j][a] * C[KORD - j][b];
      }
      acc += s[j] * T;
    }
    g[m] = acc;
  }
  int any = 0;
  flags[0] = 1;
  for (int m = KORD; m >= 1; --m) {
    if (g[m] != 0.f) any = 1;
    flags[m] = any;
  }
}

// ---------------- gated zero of CSR-build scratch ----------------
__global__ __launch_bounds__(256) void zero_kernel(int* __restrict__ p,
                                                   const int* __restrict__ flags,
                                                   int nwords) {
  if (flags[1] == 0) return;
  for (int i = blockIdx.x * 256 + threadIdx.x; i < nwords; i += gridDim.x * 256)
    p[i] = 0;
}

// ---------------- counts: out-degree at src + in-degree at dst ----------------
__global__ __launch_bounds__(256) void cnt_kernel(const int* __restrict__ src,
                                                  const int* __restrict__ dst,
                                                  int* __restrict__ deg_i,
                                                  int* __restrict__ cnt_dst,
                                                  const int* __restrict__ flags, int E) {
  if (flags[1] == 0) return;
  for (int e = blockIdx.x * 256 + threadIdx.x; e < E; e += gridDim.x * 256) {
    atomicAdd(&deg_i[src[e]], 1);
    atomicAdd(&cnt_dst[dst[e]], 1);
  }
}

__global__ __launch_bounds__(256) void dis_kernel(const int* __restrict__ deg_i,
                                                  float* __restrict__ dis,
                                                  const int* __restrict__ flags, int n) {
  if (flags[1] == 0) return;
  for (int i = blockIdx.x * 256 + threadIdx.x; i < n; i += gridDim.x * 256) {
    int d = deg_i[i];
    dis[i] = d > 0 ? 1.0f / sqrtf((float)d) : 0.f;
  }
}

// ---------------- exclusive prefix sum of cnt_dst -> rowptr[0..n] ----------------
__global__ __launch_bounds__(1024) void scan_kernel(const int* __restrict__ cnt,
                                                    int* __restrict__ rowptr,
                                                    const int* __restrict__ flags) {
  if (flags[1] == 0) return;
  __shared__ int part[1024];
  int t = threadIdx.x;
  const int chunk = (NNODES + 1023) / 1024;
  int lo = t * chunk, hi = lo + chunk;
  if (hi > NNODES) hi = NNODES;
  int s = 0;
  for (int i = lo; i < hi; ++i) s += cnt[i];
  part[t] = s;
  __syncthreads();
  for (int off = 1; off < 1024; off <<= 1) {
    int v = (t >= off) ? part[t - off] : 0;
    __syncthreads();
    part[t] += v;
    __syncthreads();
  }
  int run = (t > 0) ? part[t - 1] : 0;
  for (int i = lo; i < hi; ++i) {
    rowptr[i] = run;
    run += cnt[i];
  }
  if (t == 1023) rowptr[NNODES] = run;
}

// ---------------- CSR fill (dst-major): col[pos] = src ----------------
__global__ __launch_bounds__(256) void fill_kernel(const int* __restrict__ src,
                                                   const int* __restrict__ dst,
                                                   const int* __restrict__ rowptr,
                                                   int* __restrict__ tmpc,
                                                   int* __restrict__ col,
                                                   const int* __restrict__ flags, int E) {
  if (flags[1] == 0) return;
  for (int e = blockIdx.x * 256 + threadIdx.x; e < E; e += gridDim.x * 256) {
    int d = dst[e];
    int pos = rowptr[d] + atomicAdd(&tmpc[d], 1);
    col[pos] = src[e];
  }
}

// ---------------- W1 -> transposed bf16, K padded to 512: w1t[c][k] ----------------
__global__ __launch_bounds__(256) void w1t_kernel(const float* __restrict__ W1,
                                                  __bf16* __restrict__ w1t) {
  int idx = blockIdx.x * 256 + threadIdx.x;
  if (idx >= HIDDIM * KPAD) return;
  int c = idx >> 9, k = idx & (KPAD - 1);
  float v = (k < FIN) ? W1[(size_t)k * HIDDIM + c] : 0.f;
  w1t[(size_t)c * KPAD + k] = (__bf16)v;
}

// ---------------- fused MLP: u = relu(x@W1+b1)@W2+b2 ; out = g0*u ----------------
// 32-row blocks (100000 = 3125*32), full-K one-shot staging: block reads its
// contiguous 62.5 KB x-slab with coalesced float4s (perfect streaming), cvt to
// bf16 LDS tile [32 rows][512 k] (row pitch 1024 B), ONE barrier, then all 16
// MFMA k-chunks run straight through (B-frags from L2-hot w1t, unroll-4).
// LDS swizzle: 16B unit u of row r stored at slot u^(r&7) -> A-frag reads
// (16 rows x same unit) hit 8 distinct slots = <=2-way conflict (free).
// arena reuse after loop: hs [32][65] f32 + w2s [64][40] f32 (barrier-guarded).
__global__ __launch_bounds__(256, 4) void mlp_kernel(
    const float* __restrict__ x, const __bf16* __restrict__ w1t,
    const float* __restrict__ b1, const float* __restrict__ W2,
    const float* __restrict__ b2, const float* __restrict__ g,
    float* __restrict__ u, float* __restrict__ out, int n) {
  __shared__ __align__(16) char arena[32768];
  const int t = threadIdx.x;
  const int w = t >> 6, lane = t & 63;
  const int row0 = blockIdx.x * 32;

  // ---- stage: 32 rows x 125 float4 = 4000 coalesced 16B loads ----
#pragma unroll 4
  for (int f = t; f < 4000; f += 256) {
    int r = f / 125;
    int kg = f - r * 125;  // float4 group, k = kg*4
    float4 q = *(const float4*)(x + (size_t)(row0 + r) * FIN + kg * 4);
    bf16x4 h;
    h[0] = (__bf16)q.x; h[1] = (__bf16)q.y; h[2] = (__bf16)q.z; h[3] = (__bf16)q.w;
    int unit = kg >> 1, half = kg & 1;
    *(bf16x4*)(arena + r * 1024 + ((unit ^ (r & 7)) << 4) + (half << 3)) = h;
  }
  // zero tail k=500..511 (unit 62 upper half + unit 63)
  if (t < 32) {
    int r = t;
    *(float2*)(arena + r * 1024 + ((62 ^ (r & 7)) << 4) + 8) = make_float2(0.f, 0.f);
    *(float4*)(arena + r * 1024 + ((63 ^ (r & 7)) << 4)) =
        make_float4(0.f, 0.f, 0.f, 0.f);
  }
  __syncthreads();

  // ---- GEMM1: 16 k-chunks of 32, no further syncs ----
  const int bcol = w * 16 + (lane & 15);  // this lane's B column (= output col)
  const int koff = (lane >> 4) * 8;       // k offset within a 32-k MFMA tile
  const __bf16* wrow = w1t + (size_t)bcol * KPAD + koff;

  f32x4 acc[2] = {};
#pragma unroll 4
  for (int c = 0; c < 16; ++c) {
    bf16x8 b = *(const bf16x8*)(wrow + c * 32);
    int uu = c * 4 + (lane >> 4);
#pragma unroll
    for (int rt = 0; rt < 2; ++rt) {
      int r = rt * 16 + (lane & 15);
      bf16x8 a = *(const bf16x8*)(arena + r * 1024 + ((uu ^ (r & 7)) << 4));
      acc[rt] = __builtin_amdgcn_mfma_f32_16x16x32_bf16(a, b, acc[rt], 0, 0, 0);
    }
  }
  __syncthreads();  // all LDS reads done; arena is reused below

  // ---- epilogue: hs = relu(acc + b1) -> LDS; GEMM2 f32; fused out = g0*u ----
  float* hs = (float*)arena;             // [32][65]
  float* w2s = (float*)(arena + 8448);   // [64][40]
  for (int i = t; i < HIDDIM * NCLS; i += 256) w2s[i] = W2[i];
  {
    float bv = b1[bcol];
#pragma unroll
    for (int rt = 0; rt < 2; ++rt)
#pragma unroll
      for (int reg = 0; reg < 4; ++reg) {
        int rrow = rt * 16 + (lane >> 4) * 4 + reg;
        float v = acc[rt][reg] + bv;
        hs[rrow * 65 + bcol] = v > 0.f ? v : 0.f;
      }
  }
  __syncthreads();

  int row = t >> 3, cg = (t & 7) * 5;
  float o[5] = {};
  for (int k = 0; k < HIDDIM; ++k) {
    float a = hs[row * 65 + k];
#pragma unroll
    for (int j = 0; j < 5; ++j) o[j] += a * w2s[k * 40 + cg + j];
  }
  int gr = row0 + row;
  if (gr < n) {
    float g0 = g[0];
    float* urow = u + (size_t)gr * NCLS + cg;
    float* orow = out + (size_t)gr * NCLS + cg;
#pragma unroll
    for (int j = 0; j < 5; ++j) {
      float val = o[j] + b2[cg + j];
      urow[j] = val;
      orow[j] = g0 * val;
    }
  }
}

// ---------------- SpMV step m: uout = D^-1/2 A D^-1/2 uin ; out += g[m]*uout ----------------
// Wave per node (grid-stride); lanes 0..39 own feature columns. Matches reference
// associativity: sum over edges of (dis[src]*uin[src]), then * dis[dst].
__global__ __launch_bounds__(256) void spmv_kernel(
    const int* __restrict__ col, const int* __restrict__ rowptr,
    const float* __restrict__ dis, const float* __restrict__ uin,
    float* __restrict__ uout, float* __restrict__ out, const float* __restrict__ g,
    const int* __restrict__ flags, int m) {
  if (flags[m] == 0) return;
  int lane = threadIdx.x & 63;
  if (lane >= NCLS) return;
  int stride = gridDim.x * 4;
  for (int wid = blockIdx.x * 4 + (threadIdx.x >> 6); wid < NNODES; wid += stride) {
    int lo = rowptr[wid], hi = rowptr[wid + 1];
    float acc = 0.f;
    for (int e = lo; e < hi; ++e) {
      int s = col[e];
      acc += dis[s] * uin[(size_t)s * NCLS + lane];
    }
    acc *= dis[wid];
    size_t idx = (size_t)wid * NCLS + lane;
    uout[idx] = acc;
    out[idx] += g[m] * acc;
  }
}

// ---------------- log_softmax: one 64-lane wave per row (grid-stride) ----------------
__global__ __launch_bounds__(256) void lsm_kernel(const float* __restrict__ out,
                                                  float* __restrict__ lsm, int n) {
  int lane = threadIdx.x & 63;
  int stride = gridDim.x * 4;
  for (int wid = blockIdx.x * 4 + (threadIdx.x >> 6); wid < n; wid += stride) {
    float xv = (lane < NCLS) ? out[(size_t)wid * NCLS + lane] : -INFINITY;
    float mx = xv;
#pragma unroll
    for (int off = 32; off; off >>= 1) mx = fmaxf(mx, __shfl_xor(mx, off));
    float e = (lane < NCLS) ? expf(xv - mx) : 0.f;
    float sum = e;
#pragma unroll
    for (int off = 32; off; off >>= 1) sum += __shfl_xor(sum, off);
    float lse = logf(sum);
    if (lane < NCLS) lsm[(size_t)wid * NCLS + lane] = xv - mx - lse;
  }
}

extern "C" void kernel_launch(void* const* d_in, const int* in_sizes, int n_in,
                              void* d_out, int out_size, void* d_ws, size_t ws_size,
                              hipStream_t stream) {
  (void)n_in; (void)out_size; (void)ws_size;
  const float* x = (const float*)d_in[0];
  const int* ei = (const int*)d_in[1];
  const float* W1 = (const float*)d_in[2];
  const float* b1 = (const float*)d_in[3];
  const float* W2 = (const float*)d_in[4];
  const float* b2 = (const float*)d_in[5];
  const float* temp = (const float*)d_in[6];
  int E = in_sizes[1] / 2;
  const int* src = ei;
  const int* dst = ei + E;
  int n = NNODES;

  // ws layout in 4-byte words; total ~7.72M words (~30.9 MB)
  float* ws = (float*)d_ws;
  float* ua = ws;                          // 4,000,000 f32
  int* col = (int*)(ws + 4000000);         // 3,200,000 i32
  int* cnt_dst = (int*)(ws + 7200000);     // 100,000 i32 (zero_kernel covers this + next two)
  int* tmpc = (int*)(ws + 7300000);        // 100,000 i32
  int* deg_i = (int*)(ws + 7400000);       // 100,000 i32
  int* rowptr = (int*)(ws + 7500000);      // 100,001 i32
  float* dis = ws + 7600016;               // 100,000 f32
  float* g = ws + 7700016;                 // 16 f32
  int* flags = (int*)(ws + 7700032);       // 16 i32
  __bf16* w1t = (__bf16*)(ws + 7700048);   // 32,768 bf16 = 16,384 words

  float* lsm = (float*)d_out;            // n*40, also ping-pong scratch during prop
  float* out = (float*)d_out + 4000000;  // n*40 accumulator, final output 1

  coeff_kernel<<<1, 64, 0, stream>>>(temp, g, flags);
  zero_kernel<<<64, 256, 0, stream>>>(cnt_dst, flags, 300000);
  cnt_kernel<<<128, 256, 0, stream>>>(src, dst, deg_i, cnt_dst, flags, E);
  dis_kernel<<<64, 256, 0, stream>>>(deg_i, dis, flags, n);
  scan_kernel<<<1, 1024, 0, stream>>>(cnt_dst, rowptr, flags);
  fill_kernel<<<128, 256, 0, stream>>>(src, dst, rowptr, tmpc, col, flags, E);
  w1t_kernel<<<(HIDDIM * KPAD + 255) / 256, 256, 0, stream>>>(W1, w1t);
  mlp_kernel<<<(n + 31) / 32, 256, 0, stream>>>(x, w1t, b1, W2, b2, g, ua, out, n);
  for (int m = 1; m <= KORD; ++m) {
    float* uin = (m & 1) ? ua : lsm;
    float* uout = (m & 1) ? lsm : ua;
    spmv_kernel<<<256, 256, 0, stream>>>(col, rowptr, dis, uin, uout, out, g, flags, m);
  }
  lsm_kernel<<<1024, 256, 0, stream>>>(out, lsm, n);
}

// Round 9
// 156.117 us; speedup vs baseline: 1.0663x; 1.0663x over previous
//
#include <hip/hip_runtime.h>
#include <hip/hip_bf16.h>
#include <math.h>

#define NNODES 100000
#define FIN 500
#define KPAD 512
#define HIDDIM 64
#define NCLS 40
#define KORD 10

typedef __bf16 bf16x4 __attribute__((ext_vector_type(4)));
typedef __bf16 bf16x8 __attribute__((ext_vector_type(8)));
typedef float f32x4 __attribute__((ext_vector_type(4)));

// ---------------- polynomial coefficients + need-flags from temp ----------------
// out = sum_j C(K,j)/2^K * relu(temp[j]) * (I-A)^j (I+A)^{K-j} h = sum_m g[m] A^m h
// g[m] = sum_j s_j * T[j][m], T[j][m] = coeff of x^m in (1-x)^j (1+x)^{K-j}.
// All intermediates are integers/1024 with numerators < 2^24, exact in f32.
// flags[m] = 1 iff any g[j] != 0 for j >= m  (SpMV step m still needed).
__global__ void coeff_kernel(const float* __restrict__ temp, float* __restrict__ g,
                             int* __restrict__ flags) {
  if (threadIdx.x != 0 || blockIdx.x != 0) return;
  float C[KORD + 1][KORD + 1];
  for (int n = 0; n <= KORD; ++n)
    for (int k = 0; k <= KORD; ++k) C[n][k] = 0.f;
  for (int n = 0; n <= KORD; ++n) {
    C[n][0] = 1.f;
    for (int k = 1; k <= n; ++k) C[n][k] = C[n - 1][k - 1] + C[n - 1][k];
  }
  float s[KORD + 1];
  for (int j = 0; j <= KORD; ++j) {
    float th = temp[j] > 0.f ? temp[j] : 0.f;
    s[j] = C[KORD][j] * (1.0f / 1024.0f) * th;
  }
  for (int m = 0; m <= KORD; ++m) {
    float acc = 0.f;
    for (int j = 0; j <= KORD; ++j) {
      float T = 0.f;
      for (int a = 0; a <= m; ++a) {
        int b = m - a;
        if (a <= j && b <= KORD - j)
          T += ((a & 1) ? -1.f : 1.f) * C[j][a] * C[KORD - j][b];
      }
      acc += s[j] * T;
    }
    g[m] = acc;
  }
  int any = 0;
  flags[0] = 1;
  for (int m = KORD; m >= 1; --m) {
    if (g[m] != 0.f) any = 1;
    flags[m] = any;
  }
}

// ---------------- gated zero of CSR-build scratch ----------------
__global__ __launch_bounds__(256) void zero_kernel(int* __restrict__ p,
                                                   const int* __restrict__ flags,
                                                   int nwords) {
  if (flags[1] == 0) return;
  for (int i = blockIdx.x * 256 + threadIdx.x; i < nwords; i += gridDim.x * 256)
    p[i] = 0;
}

// ---------------- counts: out-degree at src + in-degree at dst ----------------
__global__ __launch_bounds__(256) void cnt_kernel(const int* __restrict__ src,
                                                  const int* __restrict__ dst,
                                                  int* __restrict__ deg_i,
                                                  int* __restrict__ cnt_dst,
                                                  const int* __restrict__ flags, int E) {
  if (flags[1] == 0) return;
  for (int e = blockIdx.x * 256 + threadIdx.x; e < E; e += gridDim.x * 256) {
    atomicAdd(&deg_i[src[e]], 1);
    atomicAdd(&cnt_dst[dst[e]], 1);
  }
}

__global__ __launch_bounds__(256) void dis_kernel(const int* __restrict__ deg_i,
                                                  float* __restrict__ dis,
                                                  const int* __restrict__ flags, int n) {
  if (flags[1] == 0) return;
  for (int i = blockIdx.x * 256 + threadIdx.x; i < n; i += gridDim.x * 256) {
    int d = deg_i[i];
    dis[i] = d > 0 ? 1.0f / sqrtf((float)d) : 0.f;
  }
}

// ---------------- exclusive prefix sum of cnt_dst -> rowptr[0..n] ----------------
__global__ __launch_bounds__(1024) void scan_kernel(const int* __restrict__ cnt,
                                                    int* __restrict__ rowptr,
                                                    const int* __restrict__ flags) {
  if (flags[1] == 0) return;
  __shared__ int part[1024];
  int t = threadIdx.x;
  const int chunk = (NNODES + 1023) / 1024;
  int lo = t * chunk, hi = lo + chunk;
  if (hi > NNODES) hi = NNODES;
  int s = 0;
  for (int i = lo; i < hi; ++i) s += cnt[i];
  part[t] = s;
  __syncthreads();
  for (int off = 1; off < 1024; off <<= 1) {
    int v = (t >= off) ? part[t - off] : 0;
    __syncthreads();
    part[t] += v;
    __syncthreads();
  }
  int run = (t > 0) ? part[t - 1] : 0;
  for (int i = lo; i < hi; ++i) {
    rowptr[i] = run;
    run += cnt[i];
  }
  if (t == 1023) rowptr[NNODES] = run;
}

// ---------------- CSR fill (dst-major): col[pos] = src ----------------
__global__ __launch_bounds__(256) void fill_kernel(const int* __restrict__ src,
                                                   const int* __restrict__ dst,
                                                   const int* __restrict__ rowptr,
                                                   int* __restrict__ tmpc,
                                                   int* __restrict__ col,
                                                   const int* __restrict__ flags, int E) {
  if (flags[1] == 0) return;
  for (int e = blockIdx.x * 256 + threadIdx.x; e < E; e += gridDim.x * 256) {
    int d = dst[e];
    int pos = rowptr[d] + atomicAdd(&tmpc[d], 1);
    col[pos] = src[e];
  }
}

// ---------------- W1 -> transposed bf16, K padded to 512: w1t[c][k] ----------------
__global__ __launch_bounds__(256) void w1t_kernel(const float* __restrict__ W1,
                                                  __bf16* __restrict__ w1t) {
  int idx = blockIdx.x * 256 + threadIdx.x;
  if (idx >= HIDDIM * KPAD) return;
  int c = idx >> 9, k = idx & (KPAD - 1);
  float v = (k < FIN) ? W1[(size_t)k * HIDDIM + c] : 0.f;
  w1t[(size_t)c * KPAD + k] = (__bf16)v;
}

// ---------------- fused MLP: u = relu(x@W1+b1)@W2+b2 ; out = g0*u ----------------
// Latency-oriented structure: 8 waves/block, each wave FREE-RUNS 16 rows x 64
// cols over K=512 with A-fragments loaded DIRECTLY from global x into regs
// (2 x float4 + cvt, one chunk prefetched ahead) -- no LDS staging of x, no
// per-chunk barriers, so 16 waves/CU keep many loads in flight (TLP hides
// HBM/L3 latency). Only w1t lives in LDS (64 KB, staged once, XOR-swizzled:
// 16B unit uu of col c at slot uu^(c&7) -> B-frag reads <=2-way conflicts).
// After the k-loop: barrier, arena reused for hs[128][66] f32 + w2s, GEMM2.
__global__ __launch_bounds__(512, 4) void mlp_kernel(
    const float* __restrict__ x, const __bf16* __restrict__ w1t,
    const float* __restrict__ b1, const float* __restrict__ W2,
    const float* __restrict__ b2, const float* __restrict__ g,
    float* __restrict__ u, float* __restrict__ out, int n) {
  __shared__ __align__(16) char arena[65536];
  const int t = threadIdx.x;
  const int w = t >> 6, lane = t & 63;
  const int row0 = blockIdx.x * 128;

  // ---- stage w1t (64 cols x 512 k bf16) into LDS, swizzled, coalesced ----
#pragma unroll
  for (int i = 0; i < 8; ++i) {
    int id = t + 512 * i;           // 16B chunk id, 0..4095
    int c = id >> 6, unit = id & 63;
    bf16x8 v = *(const bf16x8*)(w1t + (size_t)id * 8);
    *(bf16x8*)(arena + c * 1024 + ((unit ^ (c & 7)) << 4)) = v;
  }
  __syncthreads();

  // ---- GEMM1: wave w owns rows row0+w*16 .. +15, cols 0..63 ----
  const int arow = lane & 15;  // A row within wave tile (also B/C col index)
  const int kq = lane >> 4;    // k quarter within 32-k chunk
  int gr = row0 + w * 16 + arow;
  if (gr > NNODES - 1) gr = NNODES - 1;  // clamp; output masked later
  const float* xrow = x + (size_t)gr * FIN + kq * 8;

  f32x4 acc[4] = {};
  float4 q0 = *(const float4*)(xrow);
  float4 q1 = *(const float4*)(xrow + 4);

  for (int c = 0; c < 16; ++c) {
    float4 p0, p1;
    if (c < 14) {
      p0 = *(const float4*)(xrow + (c + 1) * 32);
      p1 = *(const float4*)(xrow + (c + 1) * 32 + 4);
    } else if (c == 14) {
      // prefetch chunk 15 (k = 480..511), masked: k >= 500 -> 0
      float v[8];
#pragma unroll
      for (int i = 0; i < 8; ++i) {
        int k = 480 + kq * 8 + i;
        v[i] = (k < FIN) ? x[(size_t)gr * FIN + k] : 0.f;
      }
      p0 = make_float4(v[0], v[1], v[2], v[3]);
      p1 = make_float4(v[4], v[5], v[6], v[7]);
    }
    bf16x8 a;
    a[0] = (__bf16)q0.x; a[1] = (__bf16)q0.y; a[2] = (__bf16)q0.z; a[3] = (__bf16)q0.w;
    a[4] = (__bf16)q1.x; a[5] = (__bf16)q1.y; a[6] = (__bf16)q1.z; a[7] = (__bf16)q1.w;
    int uu = c * 4 + kq;
#pragma unroll
    for (int ct = 0; ct < 4; ++ct) {
      int col = ct * 16 + arow;
      bf16x8 b = *(const bf16x8*)(arena + col * 1024 + ((uu ^ (col & 7)) << 4));
      acc[ct] = __builtin_amdgcn_mfma_f32_16x16x32_bf16(a, b, acc[ct], 0, 0, 0);
    }
    if (c < 15) { q0 = p0; q1 = p1; }
  }
  __syncthreads();  // all w1t LDS reads done; arena reused below

  // ---- epilogue: hs = relu(acc + b1) -> LDS [128][66]; w2s copy; GEMM2 ----
  float* hs = (float*)arena;              // 128*66*4 = 33792 B
  float* w2s = (float*)(arena + 36864);   // 64*40*4 = 10240 B
  for (int i = t; i < HIDDIM * NCLS; i += 512) w2s[i] = W2[i];
  {
#pragma unroll
    for (int ct = 0; ct < 4; ++ct) {
      float bv = b1[ct * 16 + arow];  // C/D col = lane&15 = arow
#pragma unroll
      for (int reg = 0; reg < 4; ++reg) {
        int rrow = w * 16 + kq * 4 + reg;  // C/D row = (lane>>4)*4 + reg
        float v = acc[ct][reg] + bv;
        hs[rrow * 66 + ct * 16 + arow] = v > 0.f ? v : 0.f;
      }
    }
  }
  __syncthreads();

  // GEMM2: 128 rows x 40 cols; thread -> (row, 10-col group)
  int row = t >> 2, cg = (t & 3) * 10;
  float o[10] = {};
  for (int k = 0; k < HIDDIM; ++k) {
    float a = hs[row * 66 + k];
#pragma unroll
    for (int j = 0; j < 10; ++j) o[j] += a * w2s[k * 40 + cg + j];
  }
  int gr2 = row0 + row;
  if (gr2 < n) {
    float g0 = g[0];
    float* urow = u + (size_t)gr2 * NCLS + cg;
    float* orow = out + (size_t)gr2 * NCLS + cg;
#pragma unroll
    for (int j = 0; j < 10; ++j) {
      float val = o[j] + b2[cg + j];
      urow[j] = val;
      orow[j] = g0 * val;
    }
  }
}

// ---------------- SpMV step m: uout = D^-1/2 A D^-1/2 uin ; out += g[m]*uout ----------------
// Wave per node (grid-stride); lanes 0..39 own feature columns. Matches reference
// associativity: sum over edges of (dis[src]*uin[src]), then * dis[dst].
__global__ __launch_bounds__(256) void spmv_kernel(
    const int* __restrict__ col, const int* __restrict__ rowptr,
    const float* __restrict__ dis, const float* __restrict__ uin,
    float* __restrict__ uout, float* __restrict__ out, const float* __restrict__ g,
    const int* __restrict__ flags, int m) {
  if (flags[m] == 0) return;
  int lane = threadIdx.x & 63;
  if (lane >= NCLS) return;
  int stride = gridDim.x * 4;
  for (int wid = blockIdx.x * 4 + (threadIdx.x >> 6); wid < NNODES; wid += stride) {
    int lo = rowptr[wid], hi = rowptr[wid + 1];
    float acc = 0.f;
    for (int e = lo; e < hi; ++e) {
      int s = col[e];
      acc += dis[s] * uin[(size_t)s * NCLS + lane];
    }
    acc *= dis[wid];
    size_t idx = (size_t)wid * NCLS + lane;
    uout[idx] = acc;
    out[idx] += g[m] * acc;
  }
}

// ---------------- log_softmax: one 64-lane wave per row (grid-stride) ----------------
__global__ __launch_bounds__(256) void lsm_kernel(const float* __restrict__ out,
                                                  float* __restrict__ lsm, int n) {
  int lane = threadIdx.x & 63;
  int stride = gridDim.x * 4;
  for (int wid = blockIdx.x * 4 + (threadIdx.x >> 6); wid < n; wid += stride) {
    float xv = (lane < NCLS) ? out[(size_t)wid * NCLS + lane] : -INFINITY;
    float mx = xv;
#pragma unroll
    for (int off = 32; off; off >>= 1) mx = fmaxf(mx, __shfl_xor(mx, off));
    float e = (lane < NCLS) ? expf(xv - mx) : 0.f;
    float sum = e;
#pragma unroll
    for (int off = 32; off; off >>= 1) sum += __shfl_xor(sum, off);
    float lse = logf(sum);
    if (lane < NCLS) lsm[(size_t)wid * NCLS + lane] = xv - mx - lse;
  }
}

extern "C" void kernel_launch(void* const* d_in, const int* in_sizes, int n_in,
                              void* d_out, int out_size, void* d_ws, size_t ws_size,
                              hipStream_t stream) {
  (void)n_in; (void)out_size; (void)ws_size;
  const float* x = (const float*)d_in[0];
  const int* ei = (const int*)d_in[1];
  const float* W1 = (const float*)d_in[2];
  const float* b1 = (const float*)d_in[3];
  const float* W2 = (const float*)d_in[4];
  const float* b2 = (const float*)d_in[5];
  const float* temp = (const float*)d_in[6];
  int E = in_sizes[1] / 2;
  const int* src = ei;
  const int* dst = ei + E;
  int n = NNODES;

  // ws layout in 4-byte words; total ~7.72M words (~30.9 MB)
  float* ws = (float*)d_ws;
  float* ua = ws;                          // 4,000,000 f32
  int* col = (int*)(ws + 4000000);         // 3,200,000 i32
  int* cnt_dst = (int*)(ws + 7200000);     // 100,000 i32 (zero_kernel covers this + next two)
  int* tmpc = (int*)(ws + 7300000);        // 100,000 i32
  int* deg_i = (int*)(ws + 7400000);       // 100,000 i32
  int* rowptr = (int*)(ws + 7500000);      // 100,001 i32
  float* dis = ws + 7600016;               // 100,000 f32
  float* g = ws + 7700016;                 // 16 f32
  int* flags = (int*)(ws + 7700032);       // 16 i32
  __bf16* w1t = (__bf16*)(ws + 7700048);   // 32,768 bf16 = 16,384 words

  float* lsm = (float*)d_out;            // n*40, also ping-pong scratch during prop
  float* out = (float*)d_out + 4000000;  // n*40 accumulator, final output 1

  coeff_kernel<<<1, 64, 0, stream>>>(temp, g, flags);
  zero_kernel<<<64, 256, 0, stream>>>(cnt_dst, flags, 300000);
  cnt_kernel<<<128, 256, 0, stream>>>(src, dst, deg_i, cnt_dst, flags, E);
  dis_kernel<<<64, 256, 0, stream>>>(deg_i, dis, flags, n);
  scan_kernel<<<1, 1024, 0, stream>>>(cnt_dst, rowptr, flags);
  fill_kernel<<<128, 256, 0, stream>>>(src, dst, rowptr, tmpc, col, flags, E);
  w1t_kernel<<<(HIDDIM * KPAD + 255) / 256, 256, 0, stream>>>(W1, w1t);
  mlp_kernel<<<(n + 127) / 128, 512, 0, stream>>>(x, w1t, b1, W2, b2, g, ua, out, n);
  for (int m = 1; m <= KORD; ++m) {
    float* uin = (m & 1) ? ua : lsm;
    float* uout = (m & 1) ? lsm : ua;
    spmv_kernel<<<256, 256, 0, stream>>>(col, rowptr, dis, uin, uout, out, g, flags, m);
  }
  lsm_kernel<<<1024, 256, 0, stream>>>(out, lsm, n);
}

// Round 10
// 152.395 us; speedup vs baseline: 1.0923x; 1.0244x over previous
//
#include <hip/hip_runtime.h>
#include <hip/hip_bf16.h>
#include <math.h>

#define NNODES 100000
#define FIN 500
#define KPAD 512
#define HIDDIM 64
#define NCLS 40
#define KORD 10

typedef __bf16 bf16x4 __attribute__((ext_vector_type(4)));
typedef __bf16 bf16x8 __attribute__((ext_vector_type(8)));
typedef float f32x4 __attribute__((ext_vector_type(4)));

// ---------------- polynomial coefficients + need-flags from temp ----------------
// out = sum_j C(K,j)/2^K * relu(temp[j]) * (I-A)^j (I+A)^{K-j} h = sum_m g[m] A^m h
// g[m] = sum_j s_j * T[j][m], T[j][m] = coeff of x^m in (1-x)^j (1+x)^{K-j}.
// All intermediates are integers/1024 with numerators < 2^24, exact in f32.
// flags[m] = 1 iff any g[j] != 0 for j >= m  (SpMV step m still needed).
__global__ void coeff_kernel(const float* __restrict__ temp, float* __restrict__ g,
                             int* __restrict__ flags) {
  if (threadIdx.x != 0 || blockIdx.x != 0) return;
  float C[KORD + 1][KORD + 1];
  for (int n = 0; n <= KORD; ++n)
    for (int k = 0; k <= KORD; ++k) C[n][k] = 0.f;
  for (int n = 0; n <= KORD; ++n) {
    C[n][0] = 1.f;
    for (int k = 1; k <= n; ++k) C[n][k] = C[n - 1][k - 1] + C[n - 1][k];
  }
  float s[KORD + 1];
  for (int j = 0; j <= KORD; ++j) {
    float th = temp[j] > 0.f ? temp[j] : 0.f;
    s[j] = C[KORD][j] * (1.0f / 1024.0f) * th;
  }
  for (int m = 0; m <= KORD; ++m) {
    float acc = 0.f;
    for (int j = 0; j <= KORD; ++j) {
      float T = 0.f;
      for (int a = 0; a <= m; ++a) {
        int b = m - a;
        if (a <= j && b <= KORD - j)
          T += ((a & 1) ? -1.f : 1.f) * C[j][a] * C[KORD - j][b];
      }
      acc += s[j] * T;
    }
    g[m] = acc;
  }
  int any = 0;
  flags[0] = 1;
  for (int m = KORD; m >= 1; --m) {
    if (g[m] != 0.f) any = 1;
    flags[m] = any;
  }
}

// ---------------- gated zero of CSR-build scratch ----------------
__global__ __launch_bounds__(256) void zero_kernel(int* __restrict__ p,
                                                   const int* __restrict__ flags,
                                                   int nwords) {
  if (flags[1] == 0) return;
  for (int i = blockIdx.x * 256 + threadIdx.x; i < nwords; i += gridDim.x * 256)
    p[i] = 0;
}

// ---------------- counts: out-degree at src + in-degree at dst ----------------
__global__ __launch_bounds__(256) void cnt_kernel(const int* __restrict__ src,
                                                  const int* __restrict__ dst,
                                                  int* __restrict__ deg_i,
                                                  int* __restrict__ cnt_dst,
                                                  const int* __restrict__ flags, int E) {
  if (flags[1] == 0) return;
  for (int e = blockIdx.x * 256 + threadIdx.x; e < E; e += gridDim.x * 256) {
    atomicAdd(&deg_i[src[e]], 1);
    atomicAdd(&cnt_dst[dst[e]], 1);
  }
}

__global__ __launch_bounds__(256) void dis_kernel(const int* __restrict__ deg_i,
                                                  float* __restrict__ dis,
                                                  const int* __restrict__ flags, int n) {
  if (flags[1] == 0) return;
  for (int i = blockIdx.x * 256 + threadIdx.x; i < n; i += gridDim.x * 256) {
    int d = deg_i[i];
    dis[i] = d > 0 ? 1.0f / sqrtf((float)d) : 0.f;
  }
}

// ---------------- exclusive prefix sum of cnt_dst -> rowptr[0..n] ----------------
__global__ __launch_bounds__(1024) void scan_kernel(const int* __restrict__ cnt,
                                                    int* __restrict__ rowptr,
                                                    const int* __restrict__ flags) {
  if (flags[1] == 0) return;
  __shared__ int part[1024];
  int t = threadIdx.x;
  const int chunk = (NNODES + 1023) / 1024;
  int lo = t * chunk, hi = lo + chunk;
  if (hi > NNODES) hi = NNODES;
  int s = 0;
  for (int i = lo; i < hi; ++i) s += cnt[i];
  part[t] = s;
  __syncthreads();
  for (int off = 1; off < 1024; off <<= 1) {
    int v = (t >= off) ? part[t - off] : 0;
    __syncthreads();
    part[t] += v;
    __syncthreads();
  }
  int run = (t > 0) ? part[t - 1] : 0;
  for (int i = lo; i < hi; ++i) {
    rowptr[i] = run;
    run += cnt[i];
  }
  if (t == 1023) rowptr[NNODES] = run;
}

// ---------------- CSR fill (dst-major): col[pos] = src ----------------
__global__ __launch_bounds__(256) void fill_kernel(const int* __restrict__ src,
                                                   const int* __restrict__ dst,
                                                   const int* __restrict__ rowptr,
                                                   int* __restrict__ tmpc,
                                                   int* __restrict__ col,
                                                   const int* __restrict__ flags, int E) {
  if (flags[1] == 0) return;
  for (int e = blockIdx.x * 256 + threadIdx.x; e < E; e += gridDim.x * 256) {
    int d = dst[e];
    int pos = rowptr[d] + atomicAdd(&tmpc[d], 1);
    col[pos] = src[e];
  }
}

// ---------------- W1 -> transposed bf16, K padded to 512: w1t[c][k] ----------------
__global__ __launch_bounds__(256) void w1t_kernel(const float* __restrict__ W1,
                                                  __bf16* __restrict__ w1t) {
  int idx = blockIdx.x * 256 + threadIdx.x;
  if (idx >= HIDDIM * KPAD) return;
  int c = idx >> 9, k = idx & (KPAD - 1);
  float v = (k < FIN) ? W1[(size_t)k * HIDDIM + c] : 0.f;
  w1t[(size_t)c * KPAD + k] = (__bf16)v;
}

// ---------------- fused MLP: u = relu(x@W1+b1)@W2+b2 ; out = g0*u ----------------
// Free-running waves (no inner barriers) + DEPTH-4 register prefetch ring.
// Rationale (R9 post-mortem): x is ~50% HBM-miss on replays; sustaining HBM BW
// needs ~9 KB/CU of loads in flight (Little's law). Depth-1 gave 512 B/CU ->
// 1.6 TB/s wall. Depth-4, fully unrolled (static ring indices, no scratch):
// 128 B/lane in flight -> ~128 KB/CU. Chunk 15 is register-masked (k>=500 -> 0);
// its loads stay within the mapped page (<=48 B past x for the last row only).
// w1t in LDS (64 KB, XOR-swizzled: unit uu of col c at slot uu^(c&7)).
// Epilogue: barrier, arena reused for hs[128][66] + w2s, GEMM2, out = g0*u.
__global__ __launch_bounds__(512, 4) void mlp_kernel(
    const float* __restrict__ x, const __bf16* __restrict__ w1t,
    const float* __restrict__ b1, const float* __restrict__ W2,
    const float* __restrict__ b2, const float* __restrict__ g,
    float* __restrict__ u, float* __restrict__ out, int n) {
  __shared__ __align__(16) char arena[65536];
  const int t = threadIdx.x;
  const int w = t >> 6, lane = t & 63;
  const int row0 = blockIdx.x * 128;

  // ---- stage w1t (64 cols x 512 k bf16) into LDS, swizzled, coalesced ----
#pragma unroll
  for (int i = 0; i < 8; ++i) {
    int id = t + 512 * i;           // 16B chunk id, 0..4095
    int c = id >> 6, unit = id & 63;
    bf16x8 v = *(const bf16x8*)(w1t + (size_t)id * 8);
    *(bf16x8*)(arena + c * 1024 + ((unit ^ (c & 7)) << 4)) = v;
  }
  __syncthreads();

  // ---- GEMM1: wave w owns rows row0+w*16..+15, cols 0..63; K=512 in 16 chunks ----
  const int arow = lane & 15;  // A row within wave tile (also B/C col index)
  const int kq = lane >> 4;    // k quarter within a 32-k chunk
  int gr = row0 + w * 16 + arow;
  if (gr > NNODES - 1) gr = NNODES - 1;  // clamp; output masked later
  const float* xrow = x + (size_t)gr * FIN + kq * 8;

  f32x4 acc[4] = {};
  // depth-4 prefetch ring, statically indexed via full unroll
  float4 s0a, s0b, s1a, s1b, s2a, s2b, s3a, s3b;
#define LOAD_PLAIN(A, B, c_)                       \
  A = *(const float4*)(xrow + (c_) * 32);          \
  B = *(const float4*)(xrow + (c_) * 32 + 4);
#define LOAD_TAIL(A, B)                                              \
  {                                                                  \
    A = *(const float4*)(xrow + 480);                                \
    B = *(const float4*)(xrow + 484);                                \
    int kb = 480 + kq * 8;                                           \
    if (kb + 0 >= FIN) A.x = 0.f;                                    \
    if (kb + 1 >= FIN) A.y = 0.f;                                    \
    if (kb + 2 >= FIN) A.z = 0.f;                                    \
    if (kb + 3 >= FIN) A.w = 0.f;                                    \
    if (kb + 4 >= FIN) B.x = 0.f;                                    \
    if (kb + 5 >= FIN) B.y = 0.f;                                    \
    if (kb + 6 >= FIN) B.z = 0.f;                                    \
    if (kb + 7 >= FIN) B.w = 0.f;                                    \
  }
  LOAD_PLAIN(s0a, s0b, 0)
  LOAD_PLAIN(s1a, s1b, 1)
  LOAD_PLAIN(s2a, s2b, 2)
  LOAD_PLAIN(s3a, s3b, 3)

#define DO_CHUNK(c_, QA, QB)                                                      \
  {                                                                               \
    bf16x8 a;                                                                     \
    a[0] = (__bf16)QA.x; a[1] = (__bf16)QA.y; a[2] = (__bf16)QA.z;                \
    a[3] = (__bf16)QA.w; a[4] = (__bf16)QB.x; a[5] = (__bf16)QB.y;                \
    a[6] = (__bf16)QB.z; a[7] = (__bf16)QB.w;                                     \
    int uu = (c_) * 4 + kq;                                                       \
    _Pragma("unroll") for (int ct = 0; ct < 4; ++ct) {                            \
      int col = ct * 16 + arow;                                                   \
      bf16x8 b = *(const bf16x8*)(arena + col * 1024 + ((uu ^ (col & 7)) << 4));  \
      acc[ct] = __builtin_amdgcn_mfma_f32_16x16x32_bf16(a, b, acc[ct], 0, 0, 0);  \
    }                                                                             \
  }

  DO_CHUNK(0, s0a, s0b)  LOAD_PLAIN(s0a, s0b, 4)
  DO_CHUNK(1, s1a, s1b)  LOAD_PLAIN(s1a, s1b, 5)
  DO_CHUNK(2, s2a, s2b)  LOAD_PLAIN(s2a, s2b, 6)
  DO_CHUNK(3, s3a, s3b)  LOAD_PLAIN(s3a, s3b, 7)
  DO_CHUNK(4, s0a, s0b)  LOAD_PLAIN(s0a, s0b, 8)
  DO_CHUNK(5, s1a, s1b)  LOAD_PLAIN(s1a, s1b, 9)
  DO_CHUNK(6, s2a, s2b)  LOAD_PLAIN(s2a, s2b, 10)
  DO_CHUNK(7, s3a, s3b)  LOAD_PLAIN(s3a, s3b, 11)
  DO_CHUNK(8, s0a, s0b)  LOAD_PLAIN(s0a, s0b, 12)
  DO_CHUNK(9, s1a, s1b)  LOAD_PLAIN(s1a, s1b, 13)
  DO_CHUNK(10, s2a, s2b) LOAD_PLAIN(s2a, s2b, 14)
  DO_CHUNK(11, s3a, s3b) LOAD_TAIL(s3a, s3b)
  DO_CHUNK(12, s0a, s0b)
  DO_CHUNK(13, s1a, s1b)
  DO_CHUNK(14, s2a, s2b)
  DO_CHUNK(15, s3a, s3b)
#undef DO_CHUNK
#undef LOAD_PLAIN
#undef LOAD_TAIL

  __syncthreads();  // all w1t LDS reads done; arena reused below

  // ---- epilogue: hs = relu(acc + b1) -> LDS [128][66]; w2s copy; GEMM2 ----
  float* hs = (float*)arena;              // 128*66*4 = 33792 B
  float* w2s = (float*)(arena + 36864);   // 64*40*4 = 10240 B
  for (int i = t; i < HIDDIM * NCLS; i += 512) w2s[i] = W2[i];
  {
#pragma unroll
    for (int ct = 0; ct < 4; ++ct) {
      float bv = b1[ct * 16 + arow];  // C/D col = lane&15 = arow
#pragma unroll
      for (int reg = 0; reg < 4; ++reg) {
        int rrow = w * 16 + kq * 4 + reg;  // C/D row = (lane>>4)*4 + reg
        float v = acc[ct][reg] + bv;
        hs[rrow * 66 + ct * 16 + arow] = v > 0.f ? v : 0.f;
      }
    }
  }
  __syncthreads();

  // GEMM2: 128 rows x 40 cols; thread -> (row, 10-col group)
  int row = t >> 2, cg = (t & 3) * 10;
  float o[10] = {};
  for (int k = 0; k < HIDDIM; ++k) {
    float a = hs[row * 66 + k];
#pragma unroll
    for (int j = 0; j < 10; ++j) o[j] += a * w2s[k * 40 + cg + j];
  }
  int gr2 = row0 + row;
  if (gr2 < n) {
    float g0 = g[0];
    float* urow = u + (size_t)gr2 * NCLS + cg;
    float* orow = out + (size_t)gr2 * NCLS + cg;
#pragma unroll
    for (int j = 0; j < 10; ++j) {
      float val = o[j] + b2[cg + j];
      urow[j] = val;
      orow[j] = g0 * val;
    }
  }
}

// ---------------- SpMV step m: uout = D^-1/2 A D^-1/2 uin ; out += g[m]*uout ----------------
// Wave per node (grid-stride); lanes 0..39 own feature columns. Matches reference
// associativity: sum over edges of (dis[src]*uin[src]), then * dis[dst].
__global__ __launch_bounds__(256) void spmv_kernel(
    const int* __restrict__ col, const int* __restrict__ rowptr,
    const float* __restrict__ dis, const float* __restrict__ uin,
    float* __restrict__ uout, float* __restrict__ out, const float* __restrict__ g,
    const int* __restrict__ flags, int m) {
  if (flags[m] == 0) return;
  int lane = threadIdx.x & 63;
  if (lane >= NCLS) return;
  int stride = gridDim.x * 4;
  for (int wid = blockIdx.x * 4 + (threadIdx.x >> 6); wid < NNODES; wid += stride) {
    int lo = rowptr[wid], hi = rowptr[wid + 1];
    float acc = 0.f;
    for (int e = lo; e < hi; ++e) {
      int s = col[e];
      acc += dis[s] * uin[(size_t)s * NCLS + lane];
    }
    acc *= dis[wid];
    size_t idx = (size_t)wid * NCLS + lane;
    uout[idx] = acc;
    out[idx] += g[m] * acc;
  }
}

// ---------------- log_softmax: one 64-lane wave per row (grid-stride) ----------------
__global__ __launch_bounds__(256) void lsm_kernel(const float* __restrict__ out,
                                                  float* __restrict__ lsm, int n) {
  int lane = threadIdx.x & 63;
  int stride = gridDim.x * 4;
  for (int wid = blockIdx.x * 4 + (threadIdx.x >> 6); wid < n; wid += stride) {
    float xv = (lane < NCLS) ? out[(size_t)wid * NCLS + lane] : -INFINITY;
    float mx = xv;
#pragma unroll
    for (int off = 32; off; off >>= 1) mx = fmaxf(mx, __shfl_xor(mx, off));
    float e = (lane < NCLS) ? expf(xv - mx) : 0.f;
    float sum = e;
#pragma unroll
    for (int off = 32; off; off >>= 1) sum += __shfl_xor(sum, off);
    float lse = logf(sum);
    if (lane < NCLS) lsm[(size_t)wid * NCLS + lane] = xv - mx - lse;
  }
}

extern "C" void kernel_launch(void* const* d_in, const int* in_sizes, int n_in,
                              void* d_out, int out_size, void* d_ws, size_t ws_size,
                              hipStream_t stream) {
  (void)n_in; (void)out_size; (void)ws_size;
  const float* x = (const float*)d_in[0];
  const int* ei = (const int*)d_in[1];
  const float* W1 = (const float*)d_in[2];
  const float* b1 = (const float*)d_in[3];
  const float* W2 = (const float*)d_in[4];
  const float* b2 = (const float*)d_in[5];
  const float* temp = (const float*)d_in[6];
  int E = in_sizes[1] / 2;
  const int* src = ei;
  const int* dst = ei + E;
  int n = NNODES;

  // ws layout in 4-byte words; total ~7.72M words (~30.9 MB)
  float* ws = (float*)d_ws;
  float* ua = ws;                          // 4,000,000 f32
  int* col = (int*)(ws + 4000000);         // 3,200,000 i32
  int* cnt_dst = (int*)(ws + 7200000);     // 100,000 i32 (zero_kernel covers this + next two)
  int* tmpc = (int*)(ws + 7300000);        // 100,000 i32
  int* deg_i = (int*)(ws + 7400000);       // 100,000 i32
  int* rowptr = (int*)(ws + 7500000);      // 100,001 i32
  float* dis = ws + 7600016;               // 100,000 f32
  float* g = ws + 7700016;                 // 16 f32
  int* flags = (int*)(ws + 7700032);       // 16 i32
  __bf16* w1t = (__bf16*)(ws + 7700048);   // 32,768 bf16 = 16,384 words

  float* lsm = (float*)d_out;            // n*40, also ping-pong scratch during prop
  float* out = (float*)d_out + 4000000;  // n*40 accumulator, final output 1

  coeff_kernel<<<1, 64, 0, stream>>>(temp, g, flags);
  zero_kernel<<<64, 256, 0, stream>>>(cnt_dst, flags, 300000);
  cnt_kernel<<<128, 256, 0, stream>>>(src, dst, deg_i, cnt_dst, flags, E);
  dis_kernel<<<64, 256, 0, stream>>>(deg_i, dis, flags, n);
  scan_kernel<<<1, 1024, 0, stream>>>(cnt_dst, rowptr, flags);
  fill_kernel<<<128, 256, 0, stream>>>(src, dst, rowptr, tmpc, col, flags, E);
  w1t_kernel<<<(HIDDIM * KPAD + 255) / 256, 256, 0, stream>>>(W1, w1t);
  mlp_kernel<<<(n + 127) / 128, 512, 0, stream>>>(x, w1t, b1, W2, b2, g, ua, out, n);
  for (int m = 1; m <= KORD; ++m) {
    float* uin = (m & 1) ? ua : lsm;
    float* uout = (m & 1) ? lsm : ua;
    spmv_kernel<<<256, 256, 0, stream>>>(col, rowptr, dis, uin, uout, out, g, flags, m);
  }
  lsm_kernel<<<1024, 256, 0, stream>>>(out, lsm, n);
}